// Round 1
// baseline (444.549 us; speedup 1.0000x reference)
//
#include <hip/hip_runtime.h>

// SpatialLinearAttention on MI355X — round 1: correct fp32-vector implementation.
// Pipeline: memset(ctx,sumexp) -> k_qkv (W@x per frame, store bf16)
//           -> k_ctx (exp(k)*v outer products + sumexp, atomics)
//           -> k_mbuild (M = Wout.blockdiag(ctx^T) * SCALE, softmax denom folded)
//           -> k_out (per-n q-softmax + M@q_sm + bout)

constexpr int kC  = 128;   // channels
constexpr int kF  = 16;    // frames per batch
constexpr int kN  = 4096;  // h*w
constexpr int kNT = 128;   // n tile
constexpr float kSCALE = 0.17677669529663687f; // 32^-0.5

__device__ __forceinline__ float bfu2f(unsigned int u) {
  union { unsigned int i; float f; } c; c.i = u << 16; return c.f;
}
__device__ __forceinline__ unsigned short f2bf(float f) {
  union { float f; unsigned int i; } c; c.f = f;
  unsigned int r = c.i + 0x7fffu + ((c.i >> 16) & 1u);  // RNE
  return (unsigned short)(r >> 16);
}

// ---------------------------------------------------------------- K1: qkv GEMM
// grid (32 ntiles, 3 parts, 32 frames), 256 thr. C[128x128] = Wpart @ x_tile, K=128.
__global__ __launch_bounds__(256) void k_qkv(const float* __restrict__ x,
                                             const float* __restrict__ Wqkv,
                                             unsigned short* __restrict__ qkv) {
  __shared__ float Wst[128][132];  // [k=c][o]  (transposed for contiguous a-frag reads)
  __shared__ float Xs[128][132];   // [k=c][n]
  const int ntile = blockIdx.x, part = blockIdx.y, fr = blockIdx.z;
  const int bb = fr >> 4, ff = fr & 15;
  const int tid = threadIdx.x;
  {
    int o = tid >> 5; const int c4 = (tid & 31) * 4;
    #pragma unroll
    for (int p = 0; p < 16; ++p, o += 8) {
      const float4 w = *(const float4*)&Wqkv[(part * 128 + o) * 128 + c4];
      Wst[c4 + 0][o] = w.x; Wst[c4 + 1][o] = w.y; Wst[c4 + 2][o] = w.z; Wst[c4 + 3][o] = w.w;
    }
  }
  {
    int c = tid >> 5; const int n4 = (tid & 31) * 4;
    #pragma unroll
    for (int p = 0; p < 16; ++p, c += 8) {
      const float4 v = *(const float4*)&x[(((size_t)bb * kC + c) * kF + ff) * kN + ntile * kNT + n4];
      *(float4*)&Xs[c][n4] = v;
    }
  }
  __syncthreads();
  const int u = tid >> 4, t = tid & 15;  // rows {4u..,64+4u..}, cols {4t..,64+4t..}
  float acc[8][8];
  #pragma unroll
  for (int i = 0; i < 8; ++i)
    #pragma unroll
    for (int j = 0; j < 8; ++j) acc[i][j] = 0.f;
  #pragma unroll 4
  for (int k = 0; k < 128; ++k) {
    const float4 a0 = *(const float4*)&Wst[k][4 * u];
    const float4 a1 = *(const float4*)&Wst[k][64 + 4 * u];
    const float4 b0 = *(const float4*)&Xs[k][4 * t];
    const float4 b1 = *(const float4*)&Xs[k][64 + 4 * t];
    const float a[8]  = {a0.x, a0.y, a0.z, a0.w, a1.x, a1.y, a1.z, a1.w};
    const float bv[8] = {b0.x, b0.y, b0.z, b0.w, b1.x, b1.y, b1.z, b1.w};
    #pragma unroll
    for (int i = 0; i < 8; ++i)
      #pragma unroll
      for (int j = 0; j < 8; ++j) acc[i][j] = fmaf(a[i], bv[j], acc[i][j]);
  }
  unsigned short* ob = qkv + ((size_t)fr * 384 + part * 128) * kN + ntile * kNT;
  #pragma unroll
  for (int i = 0; i < 8; ++i) {
    const int r = (i < 4) ? 4 * u + i : 64 + 4 * u + (i - 4);
    #pragma unroll
    for (int jj = 0; jj < 2; ++jj) {
      const int cb = jj ? 64 + 4 * t : 4 * t;
      ushort4 pk;
      pk.x = f2bf(acc[i][jj * 4 + 0]); pk.y = f2bf(acc[i][jj * 4 + 1]);
      pk.z = f2bf(acc[i][jj * 4 + 2]); pk.w = f2bf(acc[i][jj * 4 + 3]);
      *(ushort4*)&ob[(size_t)r * kN + cb] = pk;
    }
  }
}

// ------------------------------------------------- K2: context partials + sumexp
// grid (4 n-chunks, 4 heads, 32 frames), 256 thr. P[d][e] += exp(k[d,n])*v[e,n].
__global__ __launch_bounds__(256) void k_ctx(const unsigned short* __restrict__ qkv,
                                             float* __restrict__ ctx,
                                             float* __restrict__ sumexp) {
  __shared__ float ek[32][132];   // exp(k) [d][n]
  __shared__ float vt[128][36];   // v transposed [n][e]
  const int chunk = blockIdx.x, h = blockIdx.y, fr = blockIdx.z;
  const int tid = threadIdx.x;
  const int d = tid >> 3, g = tid & 7;
  float P0 = 0, P1 = 0, P2 = 0, P3 = 0, se = 0;
  const unsigned short* kb = qkv + ((size_t)fr * 384 + 128 + h * 32) * kN + chunk * 1024;
  const unsigned short* vb = qkv + ((size_t)fr * 384 + 256 + h * 32) * kN + chunk * 1024;
  const int srow = tid >> 3, si0 = (tid & 7) * 16;
  for (int slab = 0; slab < 8; ++slab) {
    const int n0 = slab * 128;
    {
      const uint4 r0 = *(const uint4*)&kb[(size_t)srow * kN + n0 + si0];
      const uint4 r1 = *(const uint4*)&kb[(size_t)srow * kN + n0 + si0 + 8];
      const unsigned int kw[8] = {r0.x, r0.y, r0.z, r0.w, r1.x, r1.y, r1.z, r1.w};
      #pragma unroll
      for (int j = 0; j < 8; ++j) {
        ek[srow][si0 + 2 * j + 0] = __expf(bfu2f(kw[j] & 0xffffu));
        ek[srow][si0 + 2 * j + 1] = __expf(bfu2f(kw[j] >> 16));
      }
      const uint4 s0 = *(const uint4*)&vb[(size_t)srow * kN + n0 + si0];
      const uint4 s1 = *(const uint4*)&vb[(size_t)srow * kN + n0 + si0 + 8];
      const unsigned int vw[8] = {s0.x, s0.y, s0.z, s0.w, s1.x, s1.y, s1.z, s1.w};
      #pragma unroll
      for (int j = 0; j < 8; ++j) {
        vt[si0 + 2 * j + 0][srow] = bfu2f(vw[j] & 0xffffu);
        vt[si0 + 2 * j + 1][srow] = bfu2f(vw[j] >> 16);
      }
    }
    __syncthreads();
    #pragma unroll 4
    for (int n = 0; n < 128; ++n) {
      const float a = ek[d][n];
      const float4 vv = *(const float4*)&vt[n][4 * g];
      P0 = fmaf(a, vv.x, P0); P1 = fmaf(a, vv.y, P1);
      P2 = fmaf(a, vv.z, P2); P3 = fmaf(a, vv.w, P3);
      se += a;
    }
    __syncthreads();
  }
  float* cp = ctx + (((size_t)fr * 4 + h) * 32 + d) * 32 + 4 * g;
  atomicAdd(cp + 0, P0); atomicAdd(cp + 1, P1);
  atomicAdd(cp + 2, P2); atomicAdd(cp + 3, P3);
  if (g == 0) atomicAdd(&sumexp[fr * 128 + h * 32 + d], se);
}

// -------------------------------------------- K3: M = Wout . blockdiag(ctx^T) * SCALE
// grid (32 frames), 256 thr. M[o][h*32+d] = sum_e Wout[o][h*32+e] * ctxn[h][d][e].
__global__ __launch_bounds__(256) void k_mbuild(const float* __restrict__ Wout,
                                                const float* __restrict__ ctx,
                                                const float* __restrict__ sumexp,
                                                float* __restrict__ M) {
  __shared__ float Wo[128][129];
  __shared__ float cn[4][32][33];
  const int fr = blockIdx.x, tid = threadIdx.x;
  {
    int o = tid >> 5; const int c4 = (tid & 31) * 4;
    #pragma unroll
    for (int p = 0; p < 16; ++p, o += 8) {
      const float4 w = *(const float4*)&Wout[o * 128 + c4];
      Wo[o][c4] = w.x; Wo[o][c4 + 1] = w.y; Wo[o][c4 + 2] = w.z; Wo[o][c4 + 3] = w.w;
    }
  }
  for (int i = tid; i < 4096; i += 256) {
    const int h = i >> 10, dd = (i >> 5) & 31, e = i & 31;
    const float s = sumexp[fr * 128 + h * 32 + dd];
    cn[h][dd][e] = ctx[(((size_t)fr * 4 + h) * 32 + dd) * 32 + e] * (kSCALE / (4096.f * s));
  }
  __syncthreads();
  const int c = tid & 127, hc = c >> 5, dc = c & 31;
  for (int o = tid >> 7; o < 128; o += 2) {
    float s = 0.f;
    #pragma unroll
    for (int e = 0; e < 32; ++e) s = fmaf(Wo[o][hc * 32 + e], cn[hc][dc][e], s);
    M[(size_t)fr * 16384 + o * 128 + c] = s;
  }
}

// ------------------------------------ K4: q softmax (over d within head) + M @ q_sm + bout
// grid (32 ntiles, 32 frames), 256 thr.
__global__ __launch_bounds__(256) void k_out(const unsigned short* __restrict__ qkv,
                                             const float* __restrict__ M,
                                             const float* __restrict__ bout,
                                             float* __restrict__ out) {
  __shared__ float Mst[128][132];  // [c][o]
  __shared__ float Qs[128][132];   // [c][n], softmaxed in place
  const int ntile = blockIdx.x, fr = blockIdx.y;
  const int bb = fr >> 4, ff = fr & 15;
  const int tid = threadIdx.x;
  {
    int o = tid >> 5; const int c4 = (tid & 31) * 4;
    #pragma unroll
    for (int p = 0; p < 16; ++p, o += 8) {
      const float4 m = *(const float4*)&M[(size_t)fr * 16384 + o * 128 + c4];
      Mst[c4][o] = m.x; Mst[c4 + 1][o] = m.y; Mst[c4 + 2][o] = m.z; Mst[c4 + 3][o] = m.w;
    }
  }
  {
    int c = tid >> 5; const int n4 = (tid & 31) * 4;
    #pragma unroll
    for (int p = 0; p < 16; ++p, c += 8) {
      const uint2 r = *(const uint2*)&qkv[((size_t)fr * 384 + c) * kN + ntile * kNT + n4];
      Qs[c][n4 + 0] = bfu2f(r.x & 0xffffu); Qs[c][n4 + 1] = bfu2f(r.x >> 16);
      Qs[c][n4 + 2] = bfu2f(r.y & 0xffffu); Qs[c][n4 + 3] = bfu2f(r.y >> 16);
    }
  }
  __syncthreads();
  for (int task = tid; task < 512; task += 256) {  // 4 heads x 128 cols
    const int h = task >> 7, j = task & 127;
    float mx = -1e30f;
    #pragma unroll
    for (int dd = 0; dd < 32; ++dd) mx = fmaxf(mx, Qs[h * 32 + dd][j]);
    float s = 0.f;
    #pragma unroll
    for (int dd = 0; dd < 32; ++dd) s += __expf(Qs[h * 32 + dd][j] - mx);
    const float inv = 1.f / s;
    #pragma unroll
    for (int dd = 0; dd < 32; ++dd) Qs[h * 32 + dd][j] = __expf(Qs[h * 32 + dd][j] - mx) * inv;
  }
  __syncthreads();
  const int u = tid >> 4, t = tid & 15;
  float acc[8][8];
  #pragma unroll
  for (int i = 0; i < 8; ++i)
    #pragma unroll
    for (int j = 0; j < 8; ++j) acc[i][j] = 0.f;
  #pragma unroll 4
  for (int k = 0; k < 128; ++k) {
    const float4 a0 = *(const float4*)&Mst[k][4 * u];
    const float4 a1 = *(const float4*)&Mst[k][64 + 4 * u];
    const float4 b0 = *(const float4*)&Qs[k][4 * t];
    const float4 b1 = *(const float4*)&Qs[k][64 + 4 * t];
    const float a[8]  = {a0.x, a0.y, a0.z, a0.w, a1.x, a1.y, a1.z, a1.w};
    const float bv[8] = {b0.x, b0.y, b0.z, b0.w, b1.x, b1.y, b1.z, b1.w};
    #pragma unroll
    for (int i = 0; i < 8; ++i)
      #pragma unroll
      for (int j = 0; j < 8; ++j) acc[i][j] = fmaf(a[i], bv[j], acc[i][j]);
  }
  #pragma unroll
  for (int i = 0; i < 8; ++i) {
    const int r = (i < 4) ? 4 * u + i : 64 + 4 * u + (i - 4);
    const float bo = bout[r];
    #pragma unroll
    for (int jj = 0; jj < 2; ++jj) {
      const int cb = jj ? 64 + 4 * t : 4 * t;
      float4 o4;
      o4.x = acc[i][jj * 4 + 0] + bo; o4.y = acc[i][jj * 4 + 1] + bo;
      o4.z = acc[i][jj * 4 + 2] + bo; o4.w = acc[i][jj * 4 + 3] + bo;
      *(float4*)&out[(((size_t)bb * kC + r) * kF + ff) * kN + ntile * kNT + cb] = o4;
    }
  }
}

extern "C" void kernel_launch(void* const* d_in, const int* in_sizes, int n_in,
                              void* d_out, int out_size, void* d_ws, size_t ws_size,
                              hipStream_t stream) {
  const float* x    = (const float*)d_in[0];
  const float* Wqkv = (const float*)d_in[1];
  const float* Wout = (const float*)d_in[2];
  const float* bout = (const float*)d_in[3];
  float* out = (float*)d_out;

  char* ws = (char*)d_ws;
  // ws layout: qkv bf16 [32][384][4096] | ctx f32 [32][4][32][32] | sumexp f32 [32][128] | M f32 [32][128][128]
  unsigned short* qkv = (unsigned short*)ws;                       // 100,663,296 B
  float* ctx    = (float*)(ws + 100663296u);                       //     524,288 B
  float* sumexp = (float*)(ws + 100663296u + 524288u);             //      16,384 B
  float* M      = (float*)(ws + 100663296u + 524288u + 16384u);    //   2,097,152 B
  // total 103,301,120 B

  hipMemsetAsync(ctx, 0, 524288u + 16384u, stream);  // zero atomic accumulators

  k_qkv<<<dim3(32, 3, 32), 256, 0, stream>>>(x, Wqkv, qkv);
  k_ctx<<<dim3(4, 4, 32), 256, 0, stream>>>(qkv, ctx, sumexp);
  k_mbuild<<<dim3(32), 256, 0, stream>>>(Wout, ctx, sumexp, M);
  k_out<<<dim3(32, 32), 256, 0, stream>>>(qkv, M, bout, out);
}

// Round 2
// 266.142 us; speedup vs baseline: 1.6703x; 1.6703x over previous
//
#include <hip/hip_runtime.h>

// SpatialLinearAttention on MI355X — round 2: bf16 MFMA GEMMs, n-major qkv layout.
// memset(ctx,se) -> k_qkv (MFMA W@x -> qkvT[fr][n][384] bf16)
//                -> k_ctx (exp(k)*v outer products, n-major, atomics)
//                -> k_mbuild (M = Wout.blockdiag(ctx^T)*SCALE/n/sumexp -> bf16)
//                -> k_out (q-softmax in-reg + MFMA M@q_sm + bout)

constexpr float kSCALE = 0.17677669529663687f; // 32^-0.5

typedef __attribute__((ext_vector_type(8))) short short8;   // 8 bf16 (4 VGPRs)
typedef __attribute__((ext_vector_type(4))) float f32x4;    // MFMA acc

__device__ __forceinline__ float bfu2f(unsigned int u) {
  union { unsigned int i; float f; } c; c.i = u << 16; return c.f;
}
__device__ __forceinline__ unsigned short f2bf(float f) {
  union { float f; unsigned int i; } c; c.f = f;
  unsigned int r = c.i + 0x7fffu + ((c.i >> 16) & 1u);  // RNE
  return (unsigned short)(r >> 16);
}
__device__ __forceinline__ void pack8(const float* v, unsigned short* dst16) {
  union { unsigned short u[8]; uint4 q; } t;
  #pragma unroll
  for (int i = 0; i < 8; ++i) t.u[i] = f2bf(v[i]);
  *(uint4*)dst16 = t.q;
}
// one shared swizzle formula for every bf16 LDS tile: [row][col ^ ((row&7)<<3)]
__device__ __forceinline__ int swz(int row, int col) { return row * 128 + (col ^ ((row & 7) << 3)); }

// ---------------------------------------------------------------- K1: qkv GEMM (MFMA)
// grid (96 = 32 ntiles x 3 parts, 32 frames), 256 thr.
// D[o 128][n 128] = Wpart[o][c] @ x[c][n], K=c=128; store D^T to qkvT[fr][n][part*128+o] bf16.
__global__ __launch_bounds__(256) void k_qkv(const float* __restrict__ x,
                                             const float* __restrict__ Wqkv,
                                             unsigned short* __restrict__ qkvT) {
  __shared__ unsigned short sm[32768];          // 64 KB: A [0,16384) + B [16384,32768)
  unsigned short* Ap = sm;
  unsigned short* Bp = sm + 16384;
  const int ntile = blockIdx.x & 31, part = blockIdx.x >> 5, fr = blockIdx.y;
  const int bb = fr >> 4, ff = fr & 15;
  const int tid = threadIdx.x;
  const float* xfr = x + ((size_t)bb * 2048 + ff) * 4096;   // [c][n] : c-stride 65536 floats

  // ---- stage A: W[part*128+o][c] f32 -> bf16, swizzled rows
  {
    const int c8 = (tid & 15) * 8;
    int o = tid >> 4;
    #pragma unroll
    for (int p = 0; p < 8; ++p, o += 16) {
      const float4 w0 = *(const float4*)&Wqkv[(part * 128 + o) * 128 + c8];
      const float4 w1 = *(const float4*)&Wqkv[(part * 128 + o) * 128 + c8 + 4];
      float v[8] = {w0.x, w0.y, w0.z, w0.w, w1.x, w1.y, w1.z, w1.w};
      pack8(v, &Ap[swz(o, c8)]);
    }
  }
  // ---- stage B: x[c][n] -> Bp[n][c^] via strided coalesced dword gathers
  {
    const int nn = (tid & 63) + ((tid >> 6) & 1) * 64;   // n-local 0..127
    const int cq = (tid >> 7) * 8;                       // c8 range 0..7 / 8..15
    const int ng = ntile * 128 + nn;
    #pragma unroll
    for (int p = 0; p < 8; ++p) {
      const int c8 = cq + p;
      float v[8];
      #pragma unroll
      for (int j = 0; j < 8; ++j) v[j] = xfr[(size_t)(c8 * 8 + j) * 65536 + ng];
      pack8(v, &Bp[swz(nn, c8 * 8)]);
    }
  }
  __syncthreads();

  const int l = tid & 63, w = tid >> 6;
  const int wo = (w >> 1) * 64, wn = (w & 1) * 64;
  const int lr = l & 15, lg = l >> 4;
  f32x4 acc[4][4];
  #pragma unroll
  for (int i = 0; i < 4; ++i)
    #pragma unroll
    for (int j = 0; j < 4; ++j) acc[i][j] = 0.f;

  #pragma unroll
  for (int ks = 0; ks < 4; ++ks) {
    const int k0 = ks * 32 + lg * 8;
    short8 a[4], b[4];
    #pragma unroll
    for (int i = 0; i < 4; ++i) { const int o = wo + 16 * i + lr; a[i] = *(const short8*)&Ap[swz(o, k0)]; }
    #pragma unroll
    for (int j = 0; j < 4; ++j) { const int n = wn + 16 * j + lr; b[j] = *(const short8*)&Bp[swz(n, k0)]; }
    #pragma unroll
    for (int i = 0; i < 4; ++i)
      #pragma unroll
      for (int j = 0; j < 4; ++j)
        acc[i][j] = __builtin_amdgcn_mfma_f32_16x16x32_bf16(a[i], b[j], acc[i][j], 0, 0, 0);
  }
  __syncthreads();

  // ---- epilogue: bounce D^T tile [n][o] bf16 (stride 136), then coalesced store
  unsigned short* Tb = sm;   // 17408 shorts, overlays A+B (dead now)
  #pragma unroll
  for (int i = 0; i < 4; ++i)
    #pragma unroll
    for (int j = 0; j < 4; ++j) {
      const int n = wn + 16 * j + lr;
      const int oo = wo + 16 * i + 4 * lg;
      union { unsigned short u[4]; uint2 q; } t;
      t.u[0] = f2bf(acc[i][j][0]); t.u[1] = f2bf(acc[i][j][1]);
      t.u[2] = f2bf(acc[i][j][2]); t.u[3] = f2bf(acc[i][j][3]);
      *(uint2*)&Tb[n * 136 + oo] = t.q;
    }
  __syncthreads();
  {
    const int c8 = (tid & 15) * 8;
    int n = tid >> 4;
    unsigned short* ob = qkvT + ((size_t)fr * 4096 + ntile * 128) * 384 + part * 128;
    #pragma unroll
    for (int p = 0; p < 8; ++p, n += 16) {
      uint4 q = *(const uint4*)&Tb[n * 136 + c8];
      *(uint4*)&ob[(size_t)n * 384 + c8] = q;
    }
  }
}

// ------------------------------------------------- K2: context partials + sumexp (n-major)
// grid (8 chunks, 32 frames), 256 thr. P[h][d][e] += exp(k[n][h,d]) * v[n][h,e]; se[h][d] += exp.
__global__ __launch_bounds__(256) void k_ctx(const unsigned short* __restrict__ qkvT,
                                             float* __restrict__ ctx,
                                             float* __restrict__ sumexp) {
  __shared__ float ek[64][132];   // exp(k) [n][d_all]
  __shared__ float vv[64][132];   // v      [n][e_all]
  const int chunk = blockIdx.x, fr = blockIdx.y;
  const int tid = threadIdx.x;
  const int dd = tid >> 3, g = tid & 7;
  const int nl = tid >> 2, q = tid & 3;
  const bool isk = (q < 2);
  float P[4][4], se[4];
  #pragma unroll
  for (int h = 0; h < 4; ++h) { se[h] = 0.f; P[h][0] = P[h][1] = P[h][2] = P[h][3] = 0.f; }

  for (int slab = 0; slab < 8; ++slab) {
    const int n0 = chunk * 512 + slab * 64;
    const unsigned short* src = qkvT + ((size_t)fr * 4096 + n0 + nl) * 384 + 128 + q * 64;
    float* dr = isk ? &ek[nl][(q & 1) * 64] : &vv[nl][(q & 1) * 64];
    #pragma unroll
    for (int jj = 0; jj < 8; ++jj) {
      const uint4 u = *(const uint4*)&src[jj * 8];
      float f[8];
      f[0] = bfu2f(u.x & 0xffffu); f[1] = bfu2f(u.x >> 16);
      f[2] = bfu2f(u.y & 0xffffu); f[3] = bfu2f(u.y >> 16);
      f[4] = bfu2f(u.z & 0xffffu); f[5] = bfu2f(u.z >> 16);
      f[6] = bfu2f(u.w & 0xffffu); f[7] = bfu2f(u.w >> 16);
      if (isk) {
        #pragma unroll
        for (int e = 0; e < 8; ++e) f[e] = __expf(f[e]);
      }
      *(float4*)&dr[jj * 8] = make_float4(f[0], f[1], f[2], f[3]);
      *(float4*)&dr[jj * 8 + 4] = make_float4(f[4], f[5], f[6], f[7]);
    }
    __syncthreads();
    #pragma unroll 2
    for (int n = 0; n < 64; ++n) {
      #pragma unroll
      for (int h = 0; h < 4; ++h) {
        const float a = ek[n][h * 32 + dd];
        const float4 v4 = *(const float4*)&vv[n][h * 32 + 4 * g];
        P[h][0] = fmaf(a, v4.x, P[h][0]); P[h][1] = fmaf(a, v4.y, P[h][1]);
        P[h][2] = fmaf(a, v4.z, P[h][2]); P[h][3] = fmaf(a, v4.w, P[h][3]);
        se[h] += a;
      }
    }
    __syncthreads();
  }
  #pragma unroll
  for (int h = 0; h < 4; ++h) {
    float* cp = ctx + (((size_t)fr * 4 + h) * 32 + dd) * 32 + 4 * g;
    atomicAdd(cp + 0, P[h][0]); atomicAdd(cp + 1, P[h][1]);
    atomicAdd(cp + 2, P[h][2]); atomicAdd(cp + 3, P[h][3]);
    if (g == 0) atomicAdd(&sumexp[fr * 128 + h * 32 + dd], se[h]);
  }
}

// -------------------------------------------- K3: M = Wout . blockdiag(ctx^T) * SCALE -> bf16
__global__ __launch_bounds__(256) void k_mbuild(const float* __restrict__ Wout,
                                                const float* __restrict__ ctx,
                                                const float* __restrict__ sumexp,
                                                unsigned short* __restrict__ Mbf) {
  __shared__ float Wo[128][129];
  __shared__ float cn[4][32][33];
  const int fr = blockIdx.x, tid = threadIdx.x;
  {
    int o = tid >> 5; const int c4 = (tid & 31) * 4;
    #pragma unroll
    for (int p = 0; p < 16; ++p, o += 8) {
      const float4 w = *(const float4*)&Wout[o * 128 + c4];
      Wo[o][c4] = w.x; Wo[o][c4 + 1] = w.y; Wo[o][c4 + 2] = w.z; Wo[o][c4 + 3] = w.w;
    }
  }
  for (int i = tid; i < 4096; i += 256) {
    const int h = i >> 10, dd = (i >> 5) & 31, e = i & 31;
    const float s = sumexp[fr * 128 + h * 32 + dd];
    cn[h][dd][e] = ctx[(((size_t)fr * 4 + h) * 32 + dd) * 32 + e] * (kSCALE / (4096.f * s));
  }
  __syncthreads();
  const int c = tid & 127, hc = c >> 5, dc = c & 31;
  for (int o = tid >> 7; o < 128; o += 2) {
    float s = 0.f;
    #pragma unroll
    for (int e = 0; e < 32; ++e) s = fmaf(Wo[o][hc * 32 + e], cn[hc][dc][e], s);
    Mbf[(size_t)fr * 16384 + o * 128 + c] = f2bf(s);
  }
}

// ------------------------------------ K4: q-softmax (in-reg) + MFMA M @ q_sm + bout
// grid (32 ntiles, 32 frames), 256 thr.
__global__ __launch_bounds__(256) void k_out(const unsigned short* __restrict__ qkvT,
                                             const unsigned short* __restrict__ Mbf,
                                             const float* __restrict__ bout,
                                             float* __restrict__ out) {
  __shared__ unsigned short sm[32768];
  unsigned short* Ap = sm;
  unsigned short* Bp = sm + 16384;
  const int ntile = blockIdx.x, fr = blockIdx.y;
  const int bb = fr >> 4, ff = fr & 15;
  const int tid = threadIdx.x;
  // ---- stage A: Mbf[fr][o][c] -> swizzled
  {
    const int c8 = (tid & 15) * 8;
    int o = tid >> 4;
    const unsigned short* Mf = Mbf + (size_t)fr * 16384;
    #pragma unroll
    for (int p = 0; p < 8; ++p, o += 16) {
      uint4 qv = *(const uint4*)&Mf[o * 128 + c8];
      *(uint4*)&Ap[swz(o, c8)] = qv;
    }
  }
  // ---- stage B: per-n per-head softmax of q (32 values in regs), write bf16 swizzled
  {
    const int n = tid & 127, hh = tid >> 7;
    const unsigned short* qrow = qkvT + ((size_t)fr * 4096 + ntile * 128 + n) * 384;
    #pragma unroll
    for (int hq = 0; hq < 2; ++hq) {
      const int h = hh * 2 + hq;
      float v[32];
      #pragma unroll
      for (int j = 0; j < 4; ++j) {
        const uint4 u = *(const uint4*)&qrow[h * 32 + j * 8];
        v[j*8+0] = bfu2f(u.x & 0xffffu); v[j*8+1] = bfu2f(u.x >> 16);
        v[j*8+2] = bfu2f(u.y & 0xffffu); v[j*8+3] = bfu2f(u.y >> 16);
        v[j*8+4] = bfu2f(u.z & 0xffffu); v[j*8+5] = bfu2f(u.z >> 16);
        v[j*8+6] = bfu2f(u.w & 0xffffu); v[j*8+7] = bfu2f(u.w >> 16);
      }
      float mx = v[0];
      #pragma unroll
      for (int d = 1; d < 32; ++d) mx = fmaxf(mx, v[d]);
      float s = 0.f;
      #pragma unroll
      for (int d = 0; d < 32; ++d) { v[d] = __expf(v[d] - mx); s += v[d]; }
      const float inv = 1.f / s;
      #pragma unroll
      for (int d = 0; d < 32; ++d) v[d] *= inv;
      #pragma unroll
      for (int q8 = 0; q8 < 4; ++q8) pack8(&v[q8 * 8], &Bp[swz(n, h * 32 + q8 * 8)]);
    }
  }
  __syncthreads();

  const int l = tid & 63, w = tid >> 6;
  const int wo = (w >> 1) * 64, wn = (w & 1) * 64;
  const int lr = l & 15, lg = l >> 4;
  f32x4 acc[4][4];
  #pragma unroll
  for (int i = 0; i < 4; ++i)
    #pragma unroll
    for (int j = 0; j < 4; ++j) acc[i][j] = 0.f;

  #pragma unroll
  for (int ks = 0; ks < 4; ++ks) {
    const int k0 = ks * 32 + lg * 8;
    short8 a[4], b[4];
    #pragma unroll
    for (int i = 0; i < 4; ++i) { const int o = wo + 16 * i + lr; a[i] = *(const short8*)&Ap[swz(o, k0)]; }
    #pragma unroll
    for (int j = 0; j < 4; ++j) { const int n = wn + 16 * j + lr; b[j] = *(const short8*)&Bp[swz(n, k0)]; }
    #pragma unroll
    for (int i = 0; i < 4; ++i)
      #pragma unroll
      for (int j = 0; j < 4; ++j)
        acc[i][j] = __builtin_amdgcn_mfma_f32_16x16x32_bf16(a[i], b[j], acc[i][j], 0, 0, 0);
  }

  // ---- epilogue: f32 stores, 64 B segments, + bout
  float* ofr = out + ((size_t)bb * 2048 + ff) * 4096;   // [o][n], o-stride 65536 floats
  #pragma unroll
  for (int i = 0; i < 4; ++i) {
    const int oo = wo + 16 * i + 4 * lg;
    #pragma unroll
    for (int j = 0; j < 4; ++j) {
      const int n = ntile * 128 + wn + 16 * j + lr;
      #pragma unroll
      for (int r = 0; r < 4; ++r)
        ofr[(size_t)(oo + r) * 65536 + n] = acc[i][j][r] + bout[oo + r];
    }
  }
}

extern "C" void kernel_launch(void* const* d_in, const int* in_sizes, int n_in,
                              void* d_out, int out_size, void* d_ws, size_t ws_size,
                              hipStream_t stream) {
  const float* x    = (const float*)d_in[0];
  const float* Wqkv = (const float*)d_in[1];
  const float* Wout = (const float*)d_in[2];
  const float* bout = (const float*)d_in[3];
  float* out = (float*)d_out;

  char* ws = (char*)d_ws;
  // qkvT bf16 [32][4096][384] | ctx f32 [32][4][32][32] | sumexp f32 [32][128] | Mbf bf16 [32][128][128]
  unsigned short* qkvT = (unsigned short*)ws;                          // 100,663,296 B
  float* ctxb   = (float*)(ws + 100663296u);                           //     524,288 B
  float* sumexp = (float*)(ws + 100663296u + 524288u);                 //      16,384 B
  unsigned short* Mbf = (unsigned short*)(ws + 100663296u + 524288u + 16384u); // 1,048,576 B
  // total 102,252,544 B

  hipMemsetAsync(ctxb, 0, 524288u + 16384u, stream);

  k_qkv<<<dim3(96, 32), 256, 0, stream>>>(x, Wqkv, qkvT);
  k_ctx<<<dim3(8, 32), 256, 0, stream>>>(qkvT, ctxb, sumexp);
  k_mbuild<<<dim3(32), 256, 0, stream>>>(Wout, ctxb, sumexp, Mbf);
  k_out<<<dim3(32, 32), 256, 0, stream>>>(qkvT, Mbf, bout, out);
}

// Round 3
// 199.449 us; speedup vs baseline: 2.2289x; 1.3344x over previous
//
#include <hip/hip_runtime.h>

// SpatialLinearAttention on MI355X — round 3: fused qkv+ctx+q-softmax kernel.
// memset(ctx,se) -> k_wconv (Wqkv f32 -> bf16)
//   -> k_fqkv: per (frame, 128-n tile): MFMA [384x128 = Wqkv @ x_tile];
//              q-part: softmax over d (in LDS) -> qsm global bf16 [fr][n][128]
//              k-part: exp(f32)->bf16 LDS; v-part: bf16 LDS;
//              per-head ctx[32x32] += expk @ v^T via MFMA -> f32 atomics; sumexp atomics.
//   -> k_mbuild (M = Wout.blockdiag(ctx^T)*SCALE/n/sumexp -> bf16)
//   -> k_out (MFMA M @ q_sm + bout, f32 bounce, float4 stores)

constexpr float kSCALE = 0.17677669529663687f; // 32^-0.5

typedef __attribute__((ext_vector_type(8))) short short8;   // 8 bf16 (4 VGPRs)
typedef __attribute__((ext_vector_type(4))) float f32x4;    // MFMA acc

__device__ __forceinline__ float bfu2f(unsigned int u) {
  union { unsigned int i; float f; } c; c.i = u << 16; return c.f;
}
__device__ __forceinline__ unsigned short f2bf(float f) {
  union { float f; unsigned int i; } c; c.f = f;
  unsigned int r = c.i + 0x7fffu + ((c.i >> 16) & 1u);  // RNE
  return (unsigned short)(r >> 16);
}
__device__ __forceinline__ void pack8(const float* v, unsigned short* dst16) {
  union { unsigned short u[8]; uint4 q; } t;
  #pragma unroll
  for (int i = 0; i < 8; ++i) t.u[i] = f2bf(v[i]);
  *(uint4*)dst16 = t.q;
}
// shared swizzle for all bf16 LDS tiles: elem (row,col) at row*128 + (col ^ ((row&7)<<3))
__device__ __forceinline__ int swz(int row, int col) { return row * 128 + (col ^ ((row & 7) << 3)); }

// ---------------------------------------------------------------- K0: W -> bf16
__global__ __launch_bounds__(256) void k_wconv(const float* __restrict__ W,
                                               unsigned short* __restrict__ Wbf) {
  const int i = (blockIdx.x * 256 + threadIdx.x) * 4;   // 49152 elems total
  const float4 v = *(const float4*)&W[i];
  union { unsigned short u[4]; uint2 q; } t;
  t.u[0] = f2bf(v.x); t.u[1] = f2bf(v.y); t.u[2] = f2bf(v.z); t.u[3] = f2bf(v.w);
  *(uint2*)&Wbf[i] = t.q;
}

// ---------------------------------------------------------------- K1: fused qkv
// grid (32 ntiles, 32 frames), 512 thr (8 waves: 4 o-groups x 2 n-groups, wave tile 96x64).
__global__ __launch_bounds__(512) void k_fqkv(const float* __restrict__ x,
                                              const unsigned short* __restrict__ Wbf,
                                              unsigned short* __restrict__ qsm,
                                              float* __restrict__ ctx,
                                              float* __restrict__ sumexp) {
  __shared__ __align__(16) char smem[65536];
  unsigned short* R0 = (unsigned short*)smem;            // x-tile (B), then expk [d][n]
  unsigned short* R1 = (unsigned short*)(smem + 32768);  // q-bounce [n][o], then v [e][n]
  const int ntile = blockIdx.x, fr = blockIdx.y;
  const int bb = fr >> 4, ff = fr & 15;
  const int tid = threadIdx.x;
  const float* xfr = x + ((size_t)bb * 2048 + ff) * 4096;   // [c][n], c-stride 65536 floats

  // ---- stage B: x[c][n] f32 -> R0[n][c^] bf16 (strided coalesced dword gathers)
  {
    const int nn = tid & 127, cq = tid >> 7;               // 4 c-quarters
    const int ng = ntile * 128 + nn;
    #pragma unroll
    for (int p = 0; p < 4; ++p) {
      const int c8 = cq * 4 + p;                           // group of 8 channels
      float v[8];
      #pragma unroll
      for (int j = 0; j < 8; ++j) v[j] = xfr[(size_t)(c8 * 8 + j) * 65536 + ng];
      pack8(v, &R0[swz(nn, c8 * 8)]);
    }
  }
  __syncthreads();

  const int l = tid & 63, w = tid >> 6;
  const int wo = (w >> 1) * 96, wn = (w & 1) * 64;
  const int lr = l & 15, lg = l >> 4;
  f32x4 acc[6][4];
  #pragma unroll
  for (int i = 0; i < 6; ++i)
    #pragma unroll
    for (int j = 0; j < 4; ++j) acc[i][j] = 0.f;

  // ---- GEMM: A fragments straight from global bf16 W (L2-resident, same for all blocks)
  #pragma unroll
  for (int ks = 0; ks < 4; ++ks) {
    const int k0 = ks * 32 + lg * 8;
    short8 a[6], b[4];
    #pragma unroll
    for (int i = 0; i < 6; ++i) a[i] = *(const short8*)&Wbf[(size_t)(wo + 16 * i + lr) * 128 + k0];
    #pragma unroll
    for (int j = 0; j < 4; ++j) b[j] = *(const short8*)&R0[swz(wn + 16 * j + lr, k0)];
    #pragma unroll
    for (int i = 0; i < 6; ++i)
      #pragma unroll
      for (int j = 0; j < 4; ++j)
        acc[i][j] = __builtin_amdgcn_mfma_f32_16x16x32_bf16(a[i], b[j], acc[i][j], 0, 0, 0);
  }

  // ---- E1: q-part fragments -> R1 [n][o^] bf16 (transposed bounce)
  #pragma unroll
  for (int i = 0; i < 6; ++i) {
    const int grow = wo + 16 * i;
    if (grow < 128) {
      #pragma unroll
      for (int j = 0; j < 4; ++j) {
        const int n = wn + 16 * j + lr, o4 = grow + 4 * lg;
        union { unsigned short u[4]; uint2 q; } t;
        #pragma unroll
        for (int r = 0; r < 4; ++r) t.u[r] = f2bf(acc[i][j][r]);
        *(uint2*)&R1[n * 128 + (o4 ^ ((n & 7) << 3))] = t.q;
      }
    }
  }
  __syncthreads();   // GEMM reads of R0 done; q-bounce visible

  // ---- E2a: k-part -> exp (f32) -> R0 expk [d][n^] bf16
  #pragma unroll
  for (int i = 0; i < 6; ++i) {
    const int grow = wo + 16 * i;
    if (grow >= 128 && grow < 256) {
      #pragma unroll
      for (int j = 0; j < 4; ++j) {
        const int n = wn + 16 * j + lr;
        #pragma unroll
        for (int r = 0; r < 4; ++r) {
          const int dd = grow - 128 + 4 * lg + r;
          R0[dd * 128 + (n ^ ((dd & 7) << 3))] = f2bf(__expf(acc[i][j][r]));
        }
      }
    }
  }
  // ---- q softmax over d (32 per head) from R1, store bf16 n-major
  {
    const int n = tid & 127, h = tid >> 7;
    float v[32];
    #pragma unroll
    for (int m = 0; m < 4; ++m) {
      const uint4 u = *(const uint4*)&R1[n * 128 + ((h * 32 + m * 8) ^ ((n & 7) << 3))];
      v[m*8+0] = bfu2f(u.x & 0xffffu); v[m*8+1] = bfu2f(u.x >> 16);
      v[m*8+2] = bfu2f(u.y & 0xffffu); v[m*8+3] = bfu2f(u.y >> 16);
      v[m*8+4] = bfu2f(u.z & 0xffffu); v[m*8+5] = bfu2f(u.z >> 16);
      v[m*8+6] = bfu2f(u.w & 0xffffu); v[m*8+7] = bfu2f(u.w >> 16);
    }
    float mx = v[0];
    #pragma unroll
    for (int d = 1; d < 32; ++d) mx = fmaxf(mx, v[d]);
    float s = 0.f;
    #pragma unroll
    for (int d = 0; d < 32; ++d) { v[d] = __expf(v[d] - mx); s += v[d]; }
    const float inv = 1.f / s;
    #pragma unroll
    for (int d = 0; d < 32; ++d) v[d] *= inv;
    unsigned short* qb = qsm + ((size_t)fr * 4096 + ntile * 128 + n) * 128 + h * 32;
    #pragma unroll
    for (int m = 0; m < 4; ++m) pack8(&v[m * 8], &qb[m * 8]);
  }
  __syncthreads();   // q-softmax reads of R1 done

  // ---- E2b: v-part -> R1 vv [e][n^] bf16
  #pragma unroll
  for (int i = 0; i < 6; ++i) {
    const int grow = wo + 16 * i;
    if (grow >= 256) {
      #pragma unroll
      for (int j = 0; j < 4; ++j) {
        const int n = wn + 16 * j + lr;
        #pragma unroll
        for (int r = 0; r < 4; ++r) {
          const int e = grow - 256 + 4 * lg + r;
          R1[e * 128 + (n ^ ((e & 7) << 3))] = f2bf(acc[i][j][r]);
        }
      }
    }
  }
  __syncthreads();

  // ---- ctx MFMA (waves 0-3, one head each) + sumexp (waves 4-7)
  if (w < 4) {
    const int h = w;
    f32x4 c2[2][2];
    c2[0][0] = 0.f; c2[0][1] = 0.f; c2[1][0] = 0.f; c2[1][1] = 0.f;
    #pragma unroll
    for (int ks = 0; ks < 4; ++ks) {
      const int k0 = ks * 32 + lg * 8;
      short8 a2[2], b2[2];
      #pragma unroll
      for (int i2 = 0; i2 < 2; ++i2) a2[i2] = *(const short8*)&R0[swz(h * 32 + 16 * i2 + lr, k0)];
      #pragma unroll
      for (int j2 = 0; j2 < 2; ++j2) b2[j2] = *(const short8*)&R1[swz(h * 32 + 16 * j2 + lr, k0)];
      #pragma unroll
      for (int i2 = 0; i2 < 2; ++i2)
        #pragma unroll
        for (int j2 = 0; j2 < 2; ++j2)
          c2[i2][j2] = __builtin_amdgcn_mfma_f32_16x16x32_bf16(a2[i2], b2[j2], c2[i2][j2], 0, 0, 0);
    }
    float* cp = ctx + ((size_t)fr * 4 + h) * 1024;
    #pragma unroll
    for (int i2 = 0; i2 < 2; ++i2)
      #pragma unroll
      for (int j2 = 0; j2 < 2; ++j2)
        #pragma unroll
        for (int r = 0; r < 4; ++r)
          atomicAdd(&cp[(16 * i2 + 4 * lg + r) * 32 + 16 * j2 + lr], c2[i2][j2][r]);
  } else {
    const int h = w - 4;
    const int dd = l & 31, half = l >> 5;
    const int row = h * 32 + dd;
    float s = 0.f;
    #pragma unroll
    for (int m = 0; m < 8; ++m) {
      const uint4 u = *(const uint4*)&R0[row * 128 + ((half * 64 + m * 8) ^ ((row & 7) << 3))];
      s += bfu2f(u.x & 0xffffu) + bfu2f(u.x >> 16) + bfu2f(u.y & 0xffffu) + bfu2f(u.y >> 16)
         + bfu2f(u.z & 0xffffu) + bfu2f(u.z >> 16) + bfu2f(u.w & 0xffffu) + bfu2f(u.w >> 16);
    }
    s += __shfl_xor(s, 32);
    if (half == 0) atomicAdd(&sumexp[fr * 128 + row], s);
  }
}

// -------------------------------------------- K2: M = Wout . blockdiag(ctx^T) * SCALE -> bf16
__global__ __launch_bounds__(256) void k_mbuild(const float* __restrict__ Wout,
                                                const float* __restrict__ ctx,
                                                const float* __restrict__ sumexp,
                                                unsigned short* __restrict__ Mbf) {
  __shared__ float Wo[128][129];
  __shared__ float cn[4][32][33];
  const int fr = blockIdx.x, tid = threadIdx.x;
  {
    int o = tid >> 5; const int c4 = (tid & 31) * 4;
    #pragma unroll
    for (int p = 0; p < 16; ++p, o += 8) {
      const float4 w = *(const float4*)&Wout[o * 128 + c4];
      Wo[o][c4] = w.x; Wo[o][c4 + 1] = w.y; Wo[o][c4 + 2] = w.z; Wo[o][c4 + 3] = w.w;
    }
  }
  for (int i = tid; i < 4096; i += 256) {
    const int h = i >> 10, dd = (i >> 5) & 31, e = i & 31;
    const float s = sumexp[fr * 128 + h * 32 + dd];
    cn[h][dd][e] = ctx[(((size_t)fr * 4 + h) * 32 + dd) * 32 + e] * (kSCALE / (4096.f * s));
  }
  __syncthreads();
  const int c = tid & 127, hc = c >> 5, dc = c & 31;
  for (int o = tid >> 7; o < 128; o += 2) {
    float s = 0.f;
    #pragma unroll
    for (int e = 0; e < 32; ++e) s = fmaf(Wo[o][hc * 32 + e], cn[hc][dc][e], s);
    Mbf[(size_t)fr * 16384 + o * 128 + c] = f2bf(s);
  }
}

// ------------------------------------ K3: MFMA M @ q_sm + bout, f32 bounce, float4 stores
// grid (32 ntiles, 32 frames), 256 thr.
__global__ __launch_bounds__(256) void k_out(const unsigned short* __restrict__ qsm,
                                             const unsigned short* __restrict__ Mbf,
                                             const float* __restrict__ bout,
                                             float* __restrict__ out) {
  __shared__ __align__(16) char smem[67584];
  unsigned short* Ap = (unsigned short*)smem;
  unsigned short* Bp = (unsigned short*)(smem + 32768);
  float* Ob = (float*)smem;                       // [o 128][n 132] f32, overlays A+B
  const int ntile = blockIdx.x, fr = blockIdx.y;
  const int bb = fr >> 4, ff = fr & 15;
  const int tid = threadIdx.x;
  {
    const int c8 = (tid & 15) * 8;
    int o = tid >> 4;
    const unsigned short* Mf = Mbf + (size_t)fr * 16384;
    #pragma unroll
    for (int p = 0; p < 8; ++p, o += 16) {
      uint4 qv = *(const uint4*)&Mf[o * 128 + c8];
      *(uint4*)&Ap[swz(o, c8)] = qv;
    }
  }
  {
    const int c8 = (tid & 15) * 8;
    int n = tid >> 4;
    const unsigned short* qb = qsm + ((size_t)fr * 4096 + ntile * 128) * 128;
    #pragma unroll
    for (int p = 0; p < 8; ++p, n += 16) {
      uint4 qv = *(const uint4*)&qb[n * 128 + c8];
      *(uint4*)&Bp[swz(n, c8)] = qv;
    }
  }
  __syncthreads();

  const int l = tid & 63, w = tid >> 6;
  const int wo = (w >> 1) * 64, wn = (w & 1) * 64;
  const int lr = l & 15, lg = l >> 4;
  f32x4 acc[4][4];
  #pragma unroll
  for (int i = 0; i < 4; ++i)
    #pragma unroll
    for (int j = 0; j < 4; ++j) acc[i][j] = 0.f;

  #pragma unroll
  for (int ks = 0; ks < 4; ++ks) {
    const int k0 = ks * 32 + lg * 8;
    short8 a[4], b[4];
    #pragma unroll
    for (int i = 0; i < 4; ++i) a[i] = *(const short8*)&Ap[swz(wo + 16 * i + lr, k0)];
    #pragma unroll
    for (int j = 0; j < 4; ++j) b[j] = *(const short8*)&Bp[swz(wn + 16 * j + lr, k0)];
    #pragma unroll
    for (int i = 0; i < 4; ++i)
      #pragma unroll
      for (int j = 0; j < 4; ++j)
        acc[i][j] = __builtin_amdgcn_mfma_f32_16x16x32_bf16(a[i], b[j], acc[i][j], 0, 0, 0);
  }
  __syncthreads();   // all frag reads done before overlay

  // ---- bounce to f32 [o][n] (+bout), then coalesced float4 stores
  #pragma unroll
  for (int i = 0; i < 4; ++i) {
    #pragma unroll
    for (int j = 0; j < 4; ++j) {
      const int n = wn + 16 * j + lr;
      #pragma unroll
      for (int r = 0; r < 4; ++r) {
        const int o = wo + 16 * i + 4 * lg + r;
        Ob[o * 132 + n] = acc[i][j][r] + bout[o];
      }
    }
  }
  __syncthreads();
  {
    float* ofr = out + ((size_t)bb * 2048 + ff) * 4096;   // [o][n], o-stride 65536 floats
    const int m = tid & 15;
    #pragma unroll
    for (int p = 0; p < 8; ++p) {
      const int o = p * 16 + (tid >> 4);
      float4 v0 = *(const float4*)&Ob[o * 132 + m * 4];
      float4 v1 = *(const float4*)&Ob[o * 132 + 64 + m * 4];
      *(float4*)&ofr[(size_t)o * 65536 + ntile * 128 + m * 4] = v0;
      *(float4*)&ofr[(size_t)o * 65536 + ntile * 128 + 64 + m * 4] = v1;
    }
  }
}

extern "C" void kernel_launch(void* const* d_in, const int* in_sizes, int n_in,
                              void* d_out, int out_size, void* d_ws, size_t ws_size,
                              hipStream_t stream) {
  const float* x    = (const float*)d_in[0];
  const float* Wqkv = (const float*)d_in[1];
  const float* Wout = (const float*)d_in[2];
  const float* bout = (const float*)d_in[3];
  float* out = (float*)d_out;

  char* ws = (char*)d_ws;
  // qsm bf16 [32][4096][128] | ctx f32 [32][4][32][32] | sumexp f32 [32][128] | Mbf bf16 | Wbf bf16
  unsigned short* qsm = (unsigned short*)ws;                          // 33,554,432 B
  float* ctxb   = (float*)(ws + 33554432u);                           //    524,288 B
  float* sumexp = (float*)(ws + 33554432u + 524288u);                 //     16,384 B
  unsigned short* Mbf = (unsigned short*)(ws + 34095104u);            //  1,048,576 B
  unsigned short* Wbf = (unsigned short*)(ws + 35143680u);            //     98,304 B
  // total 35,241,984 B

  hipMemsetAsync(ctxb, 0, 524288u + 16384u, stream);

  k_wconv<<<dim3(48), 256, 0, stream>>>(Wqkv, Wbf);
  k_fqkv<<<dim3(32, 32), 512, 0, stream>>>(x, Wbf, qsm, ctxb, sumexp);
  k_mbuild<<<dim3(32), 256, 0, stream>>>(Wout, ctxb, sumexp, Mbf);
  k_out<<<dim3(32, 32), 256, 0, stream>>>(qsm, Mbf, bout, out);
}